// Round 8
// baseline (47.830 us; speedup 1.0000x reference)
//
#include <hip/hip_runtime.h>

// Problem constants
#define BB 8
#define FF 256
#define TT 1024
#define CC 64
constexpr float EPS = 1e-9f;

#define BCF (BB * CC * FF)      // 131072

// ws layout (float offsets)
#define WS_NP 0                 // [512][64]            32768
#define WS_R  32768             // [B][8][128][64]      524288  (b, tq, t', c)
#define WS_FP 557056            // [8][B][64][256]      1048576 (tq-partials)

// ---------------------------------------------------------------------------
// phase 1: per (b, 16-t tile): stage x^T, xmu GEMM (K-split by wave), mu2
// (L1-hot, post-GEMM), softmax over c with inline x2, write r[b][tq][t'][c]
// + N partials. grid = 512 (b(8) x tile(64)). 3 barriers.
// ---------------------------------------------------------------------------
__global__ __launch_bounds__(256, 4) void k_phase1(
        const float* __restrict__ x, const float* __restrict__ mu,
        const float* __restrict__ prec, float* __restrict__ ws) {
    __shared__ __align__(16) float xt[16][260];       // [t][f]
    __shared__ __align__(16) float Sred[4][16][68];   // K-split partials
    __shared__ __align__(16) float rl[16][68];        // r[t][c]
    __shared__ float mu2s[CC], p2s[CC];

    const int tid = threadIdx.x;
    const int b    = blockIdx.x >> 6;
    const int tile = blockIdx.x & 63;
    const int t0   = tile * 16;
    const float* xb = x + (size_t)b * FF * TT;

    if (tid < CC) { float p = prec[tid]; p2s[tid] = p * p; }

    // stage x[b][:, t0..t0+16) transposed -> xt[t][f]
    #pragma unroll
    for (int it = 0; it < 4; ++it) {
        const int id = it * 256 + tid;
        const int f = id >> 2, seg = id & 3;
        float4 v = *(const float4*)(xb + f * TT + t0 + seg * 4);
        xt[seg * 4 + 0][f] = v.x;
        xt[seg * 4 + 1][f] = v.y;
        xt[seg * 4 + 2][f] = v.z;
        xt[seg * 4 + 3][f] = v.w;
    }
    __syncthreads();

    // xmu GEMM: wave g owns f in [g*64, g*64+64)
    {
        const int g = tid >> 6, lane = tid & 63;
        const int tr = lane & 7;
        const int c0 = (lane >> 3) * 8;
        float acc[2][8];
        #pragma unroll
        for (int i = 0; i < 2; ++i)
            #pragma unroll
            for (int j = 0; j < 8; ++j) acc[i][j] = 0.f;

        const float* mupt = mu + (size_t)c0 * FF + g * 64;
        #pragma unroll 4
        for (int kk = 0; kk < 16; ++kk) {
            const int f4 = g * 64 + kk * 4;
            float4 xv0 = *(const float4*)&xt[tr][f4];
            float4 xv1 = *(const float4*)&xt[tr + 8][f4];
            #pragma unroll
            for (int j = 0; j < 8; ++j) {
                float4 mv = *(const float4*)(mupt + j * FF + kk * 4);
                acc[0][j] += xv0.x * mv.x + xv0.y * mv.y + xv0.z * mv.z + xv0.w * mv.w;
                acc[1][j] += xv1.x * mv.x + xv1.y * mv.y + xv1.z * mv.z + xv1.w * mv.w;
            }
        }
        #pragma unroll
        for (int i = 0; i < 2; ++i) {
            *(float4*)&Sred[g][tr + 8 * i][c0] =
                make_float4(acc[i][0], acc[i][1], acc[i][2], acc[i][3]);
            *(float4*)&Sred[g][tr + 8 * i][c0 + 4] =
                make_float4(acc[i][4], acc[i][5], acc[i][6], acc[i][7]);
        }
    }

    // mu2[c] (mu rows now L1/L2-hot from the GEMM)
    {
        const int c = tid >> 2, q = tid & 3;
        const float* mp = mu + c * FF + q * 64;
        float s = 0.f;
        #pragma unroll
        for (int i = 0; i < 16; ++i) {
            float4 v = *(const float4*)(mp + i * 4);
            s += v.x * v.x + v.y * v.y + v.z * v.z + v.w * v.w;
        }
        s += __shfl_xor(s, 1);
        s += __shfl_xor(s, 2);
        if (q == 0) mu2s[c] = s;
    }
    __syncthreads();

    // K-split reduce + inline x2 + llk + softmax; write r to LDS and global
    {
        const int t = tid >> 4, kk = tid & 15;
        const int c4 = kk * 4;
        // x2[t] inline: 16 lanes per t, strided f
        float x2v = 0.f;
        #pragma unroll
        for (int q = 0; q < 16; ++q) { float v = xt[t][kk + 16 * q]; x2v += v * v; }
        x2v += __shfl_xor(x2v, 1);
        x2v += __shfl_xor(x2v, 2);
        x2v += __shfl_xor(x2v, 4);
        x2v += __shfl_xor(x2v, 8);

        float Sx = 0.f, Sy = 0.f, Sz = 0.f, Sw = 0.f;
        #pragma unroll
        for (int gg = 0; gg < 4; ++gg) {
            float4 v = *(const float4*)&Sred[gg][t][c4];
            Sx += v.x; Sy += v.y; Sz += v.z; Sw += v.w;
        }
        float l0 = -p2s[c4 + 0] * (x2v - 2.f * Sx + mu2s[c4 + 0]);
        float l1 = -p2s[c4 + 1] * (x2v - 2.f * Sy + mu2s[c4 + 1]);
        float l2 = -p2s[c4 + 2] * (x2v - 2.f * Sz + mu2s[c4 + 2]);
        float l3 = -p2s[c4 + 3] * (x2v - 2.f * Sw + mu2s[c4 + 3]);
        float m = fmaxf(fmaxf(l0, l1), fmaxf(l2, l3));
        m = fmaxf(m, __shfl_xor(m, 1));
        m = fmaxf(m, __shfl_xor(m, 2));
        m = fmaxf(m, __shfl_xor(m, 4));
        m = fmaxf(m, __shfl_xor(m, 8));
        float e0 = __expf(l0 - m), e1 = __expf(l1 - m);
        float e2 = __expf(l2 - m), e3 = __expf(l3 - m);
        float sum = e0 + e1 + e2 + e3;
        sum += __shfl_xor(sum, 1);
        sum += __shfl_xor(sum, 2);
        sum += __shfl_xor(sum, 4);
        sum += __shfl_xor(sum, 8);
        const float inv = 1.f / sum;
        float4 rv = make_float4(e0 * inv, e1 * inv, e2 * inv, e3 * inv);
        *(float4*)&rl[t][c4] = rv;
        // global write: [b][tq][t'][c], tq = t_global/128, t' = t_global%128
        const int tq = tile >> 3, tloc = (tile & 7) * 16 + t;
        *(float4*)(ws + WS_R + (((size_t)(b * 8 + tq) * 128) + tloc) * 64 + c4) = rv;
    }
    __syncthreads();

    // N partial
    if (tid < CC) {
        float ns = 0.f;
        #pragma unroll
        for (int t = 0; t < 16; ++t) ns += rl[t][tid];
        ws[WS_NP + (size_t)blockIdx.x * CC + tid] = ns;
    }
}

// ---------------------------------------------------------------------------
// phase 2: Fpart[tq][b][c][f0..f0+32) over a 128-t chunk, single-shot staging
// (one barrier, 12 float4 global loads/thread issued back-to-back).
// grid = 512: b(8) x fsl(8) x tq(8).
// ---------------------------------------------------------------------------
__global__ __launch_bounds__(256, 2) void k_phase2(
        const float* __restrict__ x, float* __restrict__ ws) {
    __shared__ __align__(16) float xs[128][36];   // [t][f'] xor-swizzled
    __shared__ __align__(16) float rs[128][68];   // [t'][c]
    const int tid = threadIdx.x;
    const int bid = blockIdx.x;
    const int b = bid >> 6, fsl = (bid >> 3) & 7, tq = bid & 7;
    const int f0 = fsl * 32;
    const int t0 = tq * 128;
    const float* xb = x + (size_t)b * FF * TT;
    const float* rb = ws + WS_R + (size_t)(b * 8 + tq) * 128 * 64;

    // stage x tile (32f x 128t) transposed with XOR swizzle on f-column
    #pragma unroll
    for (int it = 0; it < 4; ++it) {
        const int id = it * 256 + tid;            // [0,1024)
        const int ff = id >> 5, seg = id & 31;
        float4 v = *(const float4*)(xb + (f0 + ff) * TT + t0 + seg * 4);
        #pragma unroll
        for (int k = 0; k < 4; ++k) {
            const int t = seg * 4 + k;
            const float e = (k == 0) ? v.x : (k == 1) ? v.y : (k == 2) ? v.z : v.w;
            xs[t][ff ^ ((t & 7) << 2)] = e;
        }
    }
    // stage r tile (128t x 64c): linear coalesced copy
    #pragma unroll
    for (int it = 0; it < 8; ++it) {
        const int id = it * 256 + tid;            // [0,2048) float4s
        float4 v = *(const float4*)(rb + (size_t)id * 4);
        *(float4*)&rs[id >> 4][(id & 15) * 4] = v;
    }
    __syncthreads();

    const int fi = tid & 7, cg = tid >> 3;        // f=f0+fi*4.., c=cg*2+{0,1}
    float a0[4] = {0.f, 0.f, 0.f, 0.f};
    float a1[4] = {0.f, 0.f, 0.f, 0.f};
    #pragma unroll 8
    for (int t = 0; t < 128; ++t) {
        float4 xv = *(const float4*)&xs[t][(fi * 4) ^ ((t & 7) << 2)];
        float2 rv = *(const float2*)&rs[t][cg * 2];
        a0[0] += rv.x * xv.x; a0[1] += rv.x * xv.y;
        a0[2] += rv.x * xv.z; a0[3] += rv.x * xv.w;
        a1[0] += rv.y * xv.x; a1[1] += rv.y * xv.y;
        a1[2] += rv.y * xv.z; a1[3] += rv.y * xv.w;
    }

    float* fp = ws + WS_FP + (size_t)tq * BCF + (size_t)b * CC * FF + f0;
    *(float4*)(fp + (size_t)(cg * 2 + 0) * FF + fi * 4) =
        make_float4(a0[0], a0[1], a0[2], a0[3]);
    *(float4*)(fp + (size_t)(cg * 2 + 1) * FF + fi * 4) =
        make_float4(a1[0], a1[1], a1[2], a1[3]);
}

// ---------------------------------------------------------------------------
// phase 3: out[b][c][f] = (sum_p Fp - N*mu) / (N + eps). grid = 512 (b,c).
// ---------------------------------------------------------------------------
__global__ __launch_bounds__(256, 2) void k_phase3(
        const float* __restrict__ mu, const float* __restrict__ ws,
        float* __restrict__ out) {
    __shared__ float nsh[1];
    const int tid = threadIdx.x;
    const int b = blockIdx.x >> 6, c = blockIdx.x & 63;
    if (tid < 64) {
        float s = ws[WS_NP + (size_t)(b * 64 + tid) * CC + c];
        #pragma unroll
        for (int k = 1; k < 64; k <<= 1) s += __shfl_xor(s, k);
        if (tid == 0) nsh[0] = s;
    }
    __syncthreads();
    const float nr = nsh[0];
    const int f = tid;
    const float* fp = ws + WS_FP + ((size_t)b * CC + c) * FF + f;
    float fs = 0.f;
    #pragma unroll
    for (int p = 0; p < 8; ++p) fs += fp[(size_t)p * BCF];
    out[((size_t)b * CC + c) * FF + f] = (fs - nr * mu[c * FF + f]) / (nr + EPS);
}

extern "C" void kernel_launch(void* const* d_in, const int* in_sizes, int n_in,
                              void* d_out, int out_size, void* d_ws, size_t ws_size,
                              hipStream_t stream) {
    const float* x    = (const float*)d_in[0];
    const float* mu   = (const float*)d_in[1];
    const float* prec = (const float*)d_in[2];
    float* out = (float*)d_out;
    float* ws  = (float*)d_ws;

    k_phase1<<<512, 256, 0, stream>>>(x, mu, prec, ws);
    k_phase2<<<512, 256, 0, stream>>>(x, ws);
    k_phase3<<<512, 256, 0, stream>>>(mu, ws, out);
}

// Round 9
// 44.096 us; speedup vs baseline: 1.0847x; 1.0847x over previous
//
#include <hip/hip_runtime.h>

// Problem constants
#define BB 8
#define FF 256
#define TT 1024
#define CC 64
constexpr float EPS = 1e-9f;

#define BCF (BB * CC * FF)      // 131072

// ws layout (float offsets)
#define WS_NP 0                 // [512][64]            32768
#define WS_R  32768             // [B][16][64][64]      524288  (b, tq, t', c)
#define WS_FP 557056            // [16][B][64][256]     2097152 (tq-partials)

// ---------------------------------------------------------------------------
// phase 1: per (b, 16-t tile): mu2/p2 inline, stage x^T, x2 + xmu GEMM
// (8-way K-split by wave), softmax over c, write r[b][tq][t'][c] + N partials.
// grid = 512 (b(8) x tile(64)), 512 threads, 2 blocks/CU -> 4 waves/SIMD.
// ---------------------------------------------------------------------------
__global__ __launch_bounds__(512, 4) void k_phase1(
        const float* __restrict__ x, const float* __restrict__ mu,
        const float* __restrict__ prec, float* __restrict__ ws) {
    __shared__ __align__(16) float xt[16][260];       // [t][f]
    __shared__ __align__(16) float Sred[8][16][68];   // K-split partials
    __shared__ __align__(16) float rl[16][68];        // r[t][c]
    __shared__ float x2s[16];
    __shared__ float mu2s[CC], p2s[CC];

    const int tid = threadIdx.x;
    const int b    = blockIdx.x >> 6;
    const int tile = blockIdx.x & 63;
    const int t0   = tile * 16;
    const float* xb = x + (size_t)b * FF * TT;

    // mu2[c], p2[c] inline (8 lanes per c)
    {
        const int c = tid >> 3, q = tid & 7;
        const float* mp = mu + c * FF + q * 4;
        float s = 0.f;
        #pragma unroll
        for (int i = 0; i < 8; ++i) {
            float4 v = *(const float4*)(mp + i * 32);
            s += v.x * v.x + v.y * v.y + v.z * v.z + v.w * v.w;
        }
        s += __shfl_xor(s, 1);
        s += __shfl_xor(s, 2);
        s += __shfl_xor(s, 4);
        if (q == 0) mu2s[c] = s;
        if (tid < CC) { float p = prec[tid]; p2s[tid] = p * p; }
    }

    // stage x[b][:, t0..t0+16) transposed -> xt[t][f]
    #pragma unroll
    for (int it = 0; it < 2; ++it) {
        const int id = it * 512 + tid;           // [0,1024)
        const int f = id >> 2, seg = id & 3;
        float4 v = *(const float4*)(xb + f * TT + t0 + seg * 4);
        xt[seg * 4 + 0][f] = v.x;
        xt[seg * 4 + 1][f] = v.y;
        xt[seg * 4 + 2][f] = v.z;
        xt[seg * 4 + 3][f] = v.w;
    }
    __syncthreads();

    // x2[t]: 32 lanes per t-row (runs in parallel with GEMM issue)
    {
        const int t = tid >> 5, kk = tid & 31;
        float s = 0.f;
        #pragma unroll
        for (int q = 0; q < 8; ++q) { float v = xt[t][kk + 32 * q]; s += v * v; }
        s += __shfl_xor(s, 1);
        s += __shfl_xor(s, 2);
        s += __shfl_xor(s, 4);
        s += __shfl_xor(s, 8);
        s += __shfl_xor(s, 16);
        if (kk == 0) x2s[t] = s;
    }

    // xmu GEMM: wave g (0..7) owns f in [g*32, g*32+32)
    {
        const int g = tid >> 6, lane = tid & 63;
        const int tr = lane & 7;                 // t = tr, tr+8
        const int c0 = (lane >> 3) * 8;          // 8 c's
        float acc[2][8];
        #pragma unroll
        for (int i = 0; i < 2; ++i)
            #pragma unroll
            for (int j = 0; j < 8; ++j) acc[i][j] = 0.f;

        const float* mupt = mu + (size_t)c0 * FF + g * 32;
        #pragma unroll 4
        for (int kk = 0; kk < 8; ++kk) {
            const int f4 = g * 32 + kk * 4;
            float4 xv0 = *(const float4*)&xt[tr][f4];
            float4 xv1 = *(const float4*)&xt[tr + 8][f4];
            #pragma unroll
            for (int j = 0; j < 8; ++j) {
                float4 mv = *(const float4*)(mupt + j * FF + kk * 4);
                acc[0][j] += xv0.x * mv.x + xv0.y * mv.y + xv0.z * mv.z + xv0.w * mv.w;
                acc[1][j] += xv1.x * mv.x + xv1.y * mv.y + xv1.z * mv.z + xv1.w * mv.w;
            }
        }
        #pragma unroll
        for (int i = 0; i < 2; ++i) {
            *(float4*)&Sred[g][tr + 8 * i][c0] =
                make_float4(acc[i][0], acc[i][1], acc[i][2], acc[i][3]);
            *(float4*)&Sred[g][tr + 8 * i][c0 + 4] =
                make_float4(acc[i][4], acc[i][5], acc[i][6], acc[i][7]);
        }
    }
    __syncthreads();

    // K-split reduce + llk + softmax over c (32 lanes per t, 2 c per lane)
    {
        const int t = tid >> 5, kk = tid & 31;
        const int c2 = kk * 2;
        float Sx = 0.f, Sy = 0.f;
        #pragma unroll
        for (int gg = 0; gg < 8; ++gg) {
            float2 v = *(const float2*)&Sred[gg][t][c2];
            Sx += v.x; Sy += v.y;
        }
        const float x2v = x2s[t];
        float l0 = -p2s[c2 + 0] * (x2v - 2.f * Sx + mu2s[c2 + 0]);
        float l1 = -p2s[c2 + 1] * (x2v - 2.f * Sy + mu2s[c2 + 1]);
        float m = fmaxf(l0, l1);
        m = fmaxf(m, __shfl_xor(m, 1));
        m = fmaxf(m, __shfl_xor(m, 2));
        m = fmaxf(m, __shfl_xor(m, 4));
        m = fmaxf(m, __shfl_xor(m, 8));
        m = fmaxf(m, __shfl_xor(m, 16));
        float e0 = __expf(l0 - m), e1 = __expf(l1 - m);
        float sum = e0 + e1;
        sum += __shfl_xor(sum, 1);
        sum += __shfl_xor(sum, 2);
        sum += __shfl_xor(sum, 4);
        sum += __shfl_xor(sum, 8);
        sum += __shfl_xor(sum, 16);
        const float inv = 1.f / sum;
        const float r0 = e0 * inv, r1 = e1 * inv;
        rl[t][c2] = r0;
        rl[t][c2 + 1] = r1;
        // global write: [b][tq][t'][c], tq = t_global/64, t' = t_global%64
        const int tq = tile >> 2, tloc = (tile & 3) * 16 + t;
        *(float2*)(ws + WS_R + (((size_t)(b * 16 + tq) * 64) + tloc) * 64 + c2) =
            make_float2(r0, r1);
    }
    __syncthreads();

    // N partial
    if (tid < CC) {
        float ns = 0.f;
        #pragma unroll
        for (int t = 0; t < 16; ++t) ns += rl[t][tid];
        ws[WS_NP + (size_t)blockIdx.x * CC + tid] = ns;
    }
}

// ---------------------------------------------------------------------------
// phase 2: Fpart[tq][b][c][f0..f0+64) over a 64-t chunk.
// grid = 512: b(8) x fsl(4) x tq(16). 512 threads, 2c x 4f per thread.
// ---------------------------------------------------------------------------
__global__ __launch_bounds__(512, 4) void k_phase2(
        const float* __restrict__ x, float* __restrict__ ws) {
    __shared__ __align__(16) float xs[64][68];   // [t][f']
    __shared__ __align__(16) float rs[64][68];   // [t'][c]
    const int tid = threadIdx.x;
    const int bid = blockIdx.x;
    const int b   = bid >> 6;
    const int fsl = (bid >> 4) & 3;
    const int tq  = bid & 15;
    const int f0  = fsl * 64;
    const int t0  = tq * 64;
    const float* xb = x + (size_t)b * FF * TT;
    const float* rb = ws + WS_R + (size_t)(b * 16 + tq) * 64 * 64;

    // stage x tile (64f x 64t) transposed -> xs[t][f']
    #pragma unroll
    for (int it = 0; it < 2; ++it) {
        const int id = it * 512 + tid;            // [0,1024)
        const int ff = id >> 4, seg = id & 15;
        float4 v = *(const float4*)(xb + (f0 + ff) * TT + t0 + seg * 4);
        xs[seg * 4 + 0][ff] = v.x;
        xs[seg * 4 + 1][ff] = v.y;
        xs[seg * 4 + 2][ff] = v.z;
        xs[seg * 4 + 3][ff] = v.w;
    }
    // stage r tile (64t x 64c): linear coalesced copy
    #pragma unroll
    for (int it = 0; it < 2; ++it) {
        const int id = it * 512 + tid;            // [0,1024) float4s
        float4 v = *(const float4*)(rb + (size_t)id * 4);
        *(float4*)&rs[id >> 4][(id & 15) * 4] = v;
    }
    __syncthreads();

    const int fi = tid & 15, cg = tid >> 4;       // f=f0+fi*4.., c=cg*2+{0,1}
    float a0[4] = {0.f, 0.f, 0.f, 0.f};
    float a1[4] = {0.f, 0.f, 0.f, 0.f};
    #pragma unroll 8
    for (int t = 0; t < 64; ++t) {
        float4 xv = *(const float4*)&xs[t][fi * 4];
        float2 rv = *(const float2*)&rs[t][cg * 2];
        a0[0] += rv.x * xv.x; a0[1] += rv.x * xv.y;
        a0[2] += rv.x * xv.z; a0[3] += rv.x * xv.w;
        a1[0] += rv.y * xv.x; a1[1] += rv.y * xv.y;
        a1[2] += rv.y * xv.z; a1[3] += rv.y * xv.w;
    }

    float* fp = ws + WS_FP + (size_t)tq * BCF + (size_t)b * CC * FF + f0;
    *(float4*)(fp + (size_t)(cg * 2 + 0) * FF + fi * 4) =
        make_float4(a0[0], a0[1], a0[2], a0[3]);
    *(float4*)(fp + (size_t)(cg * 2 + 1) * FF + fi * 4) =
        make_float4(a1[0], a1[1], a1[2], a1[3]);
}

// ---------------------------------------------------------------------------
// phase 3: out[b][c][f] = (sum_p Fp - N*mu) / (N + eps). grid = 512 (b,c).
// ---------------------------------------------------------------------------
__global__ __launch_bounds__(256) void k_phase3(
        const float* __restrict__ mu, const float* __restrict__ ws,
        float* __restrict__ out) {
    __shared__ float nsh[1];
    const int tid = threadIdx.x;
    const int b = blockIdx.x >> 6, c = blockIdx.x & 63;
    if (tid < 64) {
        float s = ws[WS_NP + (size_t)(b * 64 + tid) * CC + c];
        #pragma unroll
        for (int k = 1; k < 64; k <<= 1) s += __shfl_xor(s, k);
        if (tid == 0) nsh[0] = s;
    }
    __syncthreads();
    const float nr = nsh[0];
    const int f = tid;
    const float* fp = ws + WS_FP + ((size_t)b * CC + c) * FF + f;
    float fs = 0.f;
    #pragma unroll
    for (int p = 0; p < 16; ++p) fs += fp[(size_t)p * BCF];
    out[((size_t)b * CC + c) * FF + f] = (fs - nr * mu[c * FF + f]) / (nr + EPS);
}

extern "C" void kernel_launch(void* const* d_in, const int* in_sizes, int n_in,
                              void* d_out, int out_size, void* d_ws, size_t ws_size,
                              hipStream_t stream) {
    const float* x    = (const float*)d_in[0];
    const float* mu   = (const float*)d_in[1];
    const float* prec = (const float*)d_in[2];
    float* out = (float*)d_out;
    float* ws  = (float*)d_ws;

    k_phase1<<<512, 512, 0, stream>>>(x, mu, prec, ws);
    k_phase2<<<512, 512, 0, stream>>>(x, ws);
    k_phase3<<<512, 256, 0, stream>>>(mu, ws, out);
}

// Round 10
// 38.896 us; speedup vs baseline: 1.2297x; 1.1337x over previous
//
#include <hip/hip_runtime.h>

// Problem constants
#define BB 8
#define FF 256
#define TT 1024
#define CC 64
constexpr float EPS = 1e-9f;

// ws layout (float offsets)
#define WS_NP 0                 // [512][64]            32768
#define WS_FP 32768             // [512][64][256]       8388608 (33.5 MB chunk partials)

// ---------------------------------------------------------------------------
// fused: per (b, 16-t tile): mu2/p2 inline, stage x^T, x2, xmu GEMM (K-split
// by wave), softmax over c -> rl in LDS, then GEMM2 (r^T x^T) from LDS tiles
// -> FP chunk partial + N partial. grid = 512 (b(8) x tile(64)).
// Phase-1 half is round-3 verbatim; GEMM2 is round-2's proven mapping.
// ---------------------------------------------------------------------------
__global__ __launch_bounds__(256, 2) void k_fused(
        const float* __restrict__ x, const float* __restrict__ mu,
        const float* __restrict__ prec, float* __restrict__ ws) {
    __shared__ __align__(16) float xt[16][260];       // [t][f]
    __shared__ __align__(16) float Sred[4][16][68];   // K-split partials
    __shared__ __align__(16) float rl[16][68];        // r[t][c]
    __shared__ float x2s[16];
    __shared__ float mu2s[CC], p2s[CC];

    const int tid = threadIdx.x;
    const int b    = blockIdx.x >> 6;
    const int tile = blockIdx.x & 63;
    const int t0   = tile * 16;
    const float* xb = x + (size_t)b * FF * TT;

    // mu2[c], p2[c] inline
    {
        const int c = tid >> 2, q = tid & 3;
        const float* mp = mu + c * FF + q * 64;
        float s = 0.f;
        #pragma unroll
        for (int i = 0; i < 16; ++i) {
            float4 v = *(const float4*)(mp + i * 4);
            s += v.x * v.x + v.y * v.y + v.z * v.z + v.w * v.w;
        }
        s += __shfl_xor(s, 1);
        s += __shfl_xor(s, 2);
        if (q == 0) mu2s[c] = s;
        if (tid < CC) { float p = prec[tid]; p2s[tid] = p * p; }
    }

    // stage x[b][:, t0..t0+16) transposed -> xt[t][f]
    #pragma unroll
    for (int it = 0; it < 4; ++it) {
        const int id = it * 256 + tid;
        const int f = id >> 2, seg = id & 3;
        float4 v = *(const float4*)(xb + f * TT + t0 + seg * 4);
        xt[seg * 4 + 0][f] = v.x;
        xt[seg * 4 + 1][f] = v.y;
        xt[seg * 4 + 2][f] = v.z;
        xt[seg * 4 + 3][f] = v.w;
    }
    __syncthreads();

    // x2[t]
    {
        const int t = tid >> 4, kk = tid & 15;
        float s = 0.f;
        #pragma unroll
        for (int q = 0; q < 16; ++q) { float v = xt[t][kk + 16 * q]; s += v * v; }
        s += __shfl_xor(s, 1);
        s += __shfl_xor(s, 2);
        s += __shfl_xor(s, 4);
        s += __shfl_xor(s, 8);
        if (kk == 0) x2s[t] = s;
    }
    __syncthreads();

    // xmu GEMM: wave g owns f in [g*64, g*64+64)
    {
        const int g = tid >> 6, lane = tid & 63;
        const int tr = lane & 7;
        const int c0 = (lane >> 3) * 8;
        float acc[2][8];
        #pragma unroll
        for (int i = 0; i < 2; ++i)
            #pragma unroll
            for (int j = 0; j < 8; ++j) acc[i][j] = 0.f;

        const float* mupt = mu + (size_t)c0 * FF + g * 64;
        #pragma unroll 4
        for (int kk = 0; kk < 16; ++kk) {
            const int f4 = g * 64 + kk * 4;
            float4 xv0 = *(const float4*)&xt[tr][f4];
            float4 xv1 = *(const float4*)&xt[tr + 8][f4];
            #pragma unroll
            for (int j = 0; j < 8; ++j) {
                float4 mv = *(const float4*)(mupt + j * FF + kk * 4);
                acc[0][j] += xv0.x * mv.x + xv0.y * mv.y + xv0.z * mv.z + xv0.w * mv.w;
                acc[1][j] += xv1.x * mv.x + xv1.y * mv.y + xv1.z * mv.z + xv1.w * mv.w;
            }
        }
        #pragma unroll
        for (int i = 0; i < 2; ++i) {
            *(float4*)&Sred[g][tr + 8 * i][c0] =
                make_float4(acc[i][0], acc[i][1], acc[i][2], acc[i][3]);
            *(float4*)&Sred[g][tr + 8 * i][c0 + 4] =
                make_float4(acc[i][4], acc[i][5], acc[i][6], acc[i][7]);
        }
    }
    __syncthreads();

    // K-split reduce + llk + softmax -> rl (LDS only; no global r)
    {
        const int t = tid >> 4, kk = tid & 15;
        const int c4 = kk * 4;
        float Sx = 0.f, Sy = 0.f, Sz = 0.f, Sw = 0.f;
        #pragma unroll
        for (int gg = 0; gg < 4; ++gg) {
            float4 v = *(const float4*)&Sred[gg][t][c4];
            Sx += v.x; Sy += v.y; Sz += v.z; Sw += v.w;
        }
        const float x2v = x2s[t];
        float l0 = -p2s[c4 + 0] * (x2v - 2.f * Sx + mu2s[c4 + 0]);
        float l1 = -p2s[c4 + 1] * (x2v - 2.f * Sy + mu2s[c4 + 1]);
        float l2 = -p2s[c4 + 2] * (x2v - 2.f * Sz + mu2s[c4 + 2]);
        float l3 = -p2s[c4 + 3] * (x2v - 2.f * Sw + mu2s[c4 + 3]);
        float m = fmaxf(fmaxf(l0, l1), fmaxf(l2, l3));
        m = fmaxf(m, __shfl_xor(m, 1));
        m = fmaxf(m, __shfl_xor(m, 2));
        m = fmaxf(m, __shfl_xor(m, 4));
        m = fmaxf(m, __shfl_xor(m, 8));
        float e0 = __expf(l0 - m), e1 = __expf(l1 - m);
        float e2 = __expf(l2 - m), e3 = __expf(l3 - m);
        float sum = e0 + e1 + e2 + e3;
        sum += __shfl_xor(sum, 1);
        sum += __shfl_xor(sum, 2);
        sum += __shfl_xor(sum, 4);
        sum += __shfl_xor(sum, 8);
        const float inv = 1.f / sum;
        *(float4*)&rl[t][c4] = make_float4(e0 * inv, e1 * inv, e2 * inv, e3 * inv);
    }
    __syncthreads();

    // N partial
    if (tid < CC) {
        float ns = 0.f;
        #pragma unroll
        for (int t = 0; t < 16; ++t) ns += rl[t][tid];
        ws[WS_NP + (size_t)blockIdx.x * CC + tid] = ns;
    }

    // GEMM2: FP[chunk][c][f] = sum_t rl[t][c] * xt[t][f]  (round-2 mapping)
    {
        const int fc = tid & 15;       // f = fc*4 + 64*q (strided: 2-way banks)
        const int c0 = (tid >> 4) * 4; // 4 c's
        float a2[4][4][4];             // [j][q][e]
        #pragma unroll
        for (int j = 0; j < 4; ++j)
            #pragma unroll
            for (int q = 0; q < 4; ++q)
                #pragma unroll
                for (int e = 0; e < 4; ++e) a2[j][q][e] = 0.f;

        #pragma unroll 4
        for (int t = 0; t < 16; ++t) {
            float4 rv = *(const float4*)&rl[t][c0];
            #pragma unroll
            for (int q = 0; q < 4; ++q) {
                float4 xv = *(const float4*)&xt[t][fc * 4 + 64 * q];
                a2[0][q][0] += rv.x * xv.x; a2[0][q][1] += rv.x * xv.y;
                a2[0][q][2] += rv.x * xv.z; a2[0][q][3] += rv.x * xv.w;
                a2[1][q][0] += rv.y * xv.x; a2[1][q][1] += rv.y * xv.y;
                a2[1][q][2] += rv.y * xv.z; a2[1][q][3] += rv.y * xv.w;
                a2[2][q][0] += rv.z * xv.x; a2[2][q][1] += rv.z * xv.y;
                a2[2][q][2] += rv.z * xv.z; a2[2][q][3] += rv.z * xv.w;
                a2[3][q][0] += rv.w * xv.x; a2[3][q][1] += rv.w * xv.y;
                a2[3][q][2] += rv.w * xv.z; a2[3][q][3] += rv.w * xv.w;
            }
        }
        float* fp = ws + WS_FP + (size_t)blockIdx.x * CC * FF;
        #pragma unroll
        for (int j = 0; j < 4; ++j)
            #pragma unroll
            for (int q = 0; q < 4; ++q)
                *(float4*)(fp + (size_t)(c0 + j) * FF + fc * 4 + 64 * q) =
                    make_float4(a2[j][q][0], a2[j][q][1], a2[j][q][2], a2[j][q][3]);
    }
}

// ---------------------------------------------------------------------------
// phase 3: out[b][c][f] = (sum_{p<64} FP[b*64+p][c][f] - N*mu) / (N + eps)
// grid = 512 (b,c), 256 threads (f).
// ---------------------------------------------------------------------------
__global__ __launch_bounds__(256, 2) void k_phase3(
        const float* __restrict__ mu, const float* __restrict__ ws,
        float* __restrict__ out) {
    __shared__ float nsh[1];
    const int tid = threadIdx.x;
    const int b = blockIdx.x >> 6, c = blockIdx.x & 63;
    if (tid < 64) {
        float s = ws[WS_NP + (size_t)(b * 64 + tid) * CC + c];
        #pragma unroll
        for (int k = 1; k < 64; k <<= 1) s += __shfl_xor(s, k);
        if (tid == 0) nsh[0] = s;
    }
    __syncthreads();
    const float nr = nsh[0];
    const int f = tid;
    const float* fp = ws + WS_FP + ((size_t)(b * 64) * CC + c) * FF + f;
    float fs = 0.f;
    #pragma unroll 8
    for (int p = 0; p < 64; ++p) fs += fp[(size_t)p * CC * FF];
    out[((size_t)b * CC + c) * FF + f] = (fs - nr * mu[c * FF + f]) / (nr + EPS);
}

extern "C" void kernel_launch(void* const* d_in, const int* in_sizes, int n_in,
                              void* d_out, int out_size, void* d_ws, size_t ws_size,
                              hipStream_t stream) {
    const float* x    = (const float*)d_in[0];
    const float* mu   = (const float*)d_in[1];
    const float* prec = (const float*)d_in[2];
    float* out = (float*)d_out;
    float* ws  = (float*)d_ws;

    k_fused<<<512, 256, 0, stream>>>(x, mu, prec, ws);
    k_phase3<<<512, 256, 0, stream>>>(mu, ws, out);
}